// Round 3
// baseline (325.473 us; speedup 1.0000x reference)
//
#include <hip/hip_runtime.h>

// VQ-VAE quantization forward for MI355X (gfx950).
// outputs (concat in d_out, fp32): quantized_ [16*4096*256], commitment_loss [1], perplexity [1]
//
// v4: minimize per-CU VMEM + LDS bytes (the measured walls of v2/v3).
//   - 512 blocks x 512 threads (8 waves). Block owns 128 rows. Wave (rp,h): rows rp*32..+31,
//     code half h (256 codes). A resident in regs (64 VGPR); each B-fragment ds_read feeds
//     TWO MFMAs (1:2 ratio, half of v2's LDS traffic).
//   - B staged via global_load_lds (direct-to-LDS, no VGPR/L1-return cost), double-buffered
//     16 KB steps (tile for h0 + tile for h1), one barrier per step, shared by all 8 waves:
//     B bytes through VMEM = 256 KB/block vs 2 MB/block in v3.
//   - Output is exactly the gathered raw codebook row (x + sg(q-x) -> q; (q+q)/2 = q).
//     Loss via ||x||^2 + cA[c] + cB[c]*score, no x re-read.
//   - vq_final merged: last block (device ticket) computes scalars with atomic reads.
//   - Score path bit-identical to v2/v3 (same fragments, K-order, -bias init, strict-> argmax).

typedef _Float16 half8_t __attribute__((ext_vector_type(8)));
typedef _Float16 half4_t __attribute__((ext_vector_type(4)));
typedef float f32x4 __attribute__((ext_vector_type(4)));

static constexpr int kRows = 65536;   // N*T
static constexpr int kD = 256;
static constexpr int kM = 512;
static constexpr int kBM = 128;       // rows per block

typedef const unsigned int __attribute__((address_space(1)))* gas_t;
typedef unsigned int __attribute__((address_space(3)))* las_t;

// ---------------- prep: normalize codebook -> fp16 in MFMA B-fragment order, bias, cA/cB, zero hist/loss/cnt
// swz layout (halves): [group g=c>>4][ko=k>>5][lane = qd*16 + (c&15)][j = k&7], qd=(k>>3)&3.
__global__ void vq_prep(const float* __restrict__ emb, _Float16* __restrict__ swz,
                        float* __restrict__ bias, float2* __restrict__ cab,
                        unsigned int* __restrict__ hist, float* __restrict__ loss,
                        unsigned int* __restrict__ cnt) {
    const int j = blockIdx.x;       // code row, 512 blocks
    const int lane = threadIdx.x;   // 64 threads = 1 wave
    float4 v = ((const float4*)(emb + j * kD))[lane];
    float ss = v.x * v.x + v.y * v.y + v.z * v.z + v.w * v.w;
    #pragma unroll
    for (int off = 32; off > 0; off >>= 1) ss += __shfl_xor(ss, off);
    const float s = sqrtf(ss) + 1e-4f;      // ||emb_raw|| + 1e-4
    const float scale = 1.0f / s;
    if (lane == 0) {
        bias[j] = 0.5f * ss * scale * scale;            // 0.5*||e_norm||^2
        cab[j] = make_float2(ss * (1.0f - scale),       // cA = q2*(1-1/s)
                             -2.0f * s);                // cB
    }
    half4_t h;
    h[0] = (_Float16)(v.x * scale);
    h[1] = (_Float16)(v.y * scale);
    h[2] = (_Float16)(v.z * scale);
    h[3] = (_Float16)(v.w * scale);
    const int k0 = lane * 4;
    const int ko = k0 >> 5;
    const int qd = (k0 >> 3) & 3;
    const int jj = k0 & 7;
    const int off_h = (j >> 4) * 4096 + ko * 512 + (qd * 16 + (j & 15)) * 8 + jj;
    *(half4_t*)(swz + off_h) = h;
    if (j == 0) {
        for (int b = lane; b < kM; b += 64) hist[b] = 0u;
        if (lane == 0) { loss[0] = 0.0f; cnt[0] = 0u; }
    }
}

// ---------------- main: staged B (1:2 ds_read:MFMA), 32 rows/wave, code-split, ticket final ----
__global__ __launch_bounds__(512, 4) void vq_main(
    const float* __restrict__ x, const float* __restrict__ emb,
    const _Float16* __restrict__ bswz, const float* __restrict__ bias,
    const float2* __restrict__ cab, unsigned int* __restrict__ hist,
    float* __restrict__ loss_accum, unsigned int* __restrict__ cnt,
    float* __restrict__ out) {
    __shared__ _Float16 bb[2][2][4096];     // [buf][h][halves] = 32 KB, 16-code tiles
    __shared__ float lbv[kBM][2];           // per-row best score, per code-half
    __shared__ int   lbi[kBM][2];           // per-row best index, per code-half
    __shared__ float lssq[kBM];             // per-row ||x||^2
    __shared__ int   lidx[kBM];             // per-row winner
    __shared__ float lred[2];

    const int t = threadIdx.x;              // 0..511, 8 waves
    const int wave = t >> 6;
    const int lane = t & 63;
    const int ln = lane & 15;
    const int qd = lane >> 4;
    const int rp = wave & 3;                // row-pair 0..3
    const int h = wave >> 2;                // code half 0..1
    const int row0 = blockIdx.x * kBM;
    const int r0 = row0 + rp * 32;          // wave's 32 rows

    // issue stage 0 (tiles g=0 and g=16) into buf 0: 512 thr x 2 x 16 B direct-to-LDS
    {
        const _Float16* s0 = bswz + t * 8;
        __builtin_amdgcn_global_load_lds((gas_t)(const void*)s0,
                                         (las_t)(void*)(&bb[0][0][t * 8]), 16, 0, 0);
        const _Float16* s1 = bswz + 16 * 4096 + t * 8;
        __builtin_amdgcn_global_load_lds((gas_t)(const void*)s1,
                                         (las_t)(void*)(&bb[0][1][t * 8]), 16, 0, 0);
    }
    float bias_cur = bias[h * 256 + ln];

    // A fragments (two 16-row sets), loaded once; ||x||^2 per row in fp32
    half8_t a0[8], a1[8];
    float ssq0 = 0.0f, ssq1 = 0.0f;
    {
        const float* xr0 = x + (size_t)(r0 + ln) * kD + qd * 8;
        const float* xr1 = xr0 + 16 * kD;
        #pragma unroll
        for (int ko = 0; ko < 8; ++ko) {
            const float4 u0 = *(const float4*)(xr0 + ko * 32);
            const float4 u1 = *(const float4*)(xr0 + ko * 32 + 4);
            const float4 w0 = *(const float4*)(xr1 + ko * 32);
            const float4 w1 = *(const float4*)(xr1 + ko * 32 + 4);
            half8_t h0, h1;
            h0[0] = (_Float16)u0.x; h0[1] = (_Float16)u0.y;
            h0[2] = (_Float16)u0.z; h0[3] = (_Float16)u0.w;
            h0[4] = (_Float16)u1.x; h0[5] = (_Float16)u1.y;
            h0[6] = (_Float16)u1.z; h0[7] = (_Float16)u1.w;
            h1[0] = (_Float16)w0.x; h1[1] = (_Float16)w0.y;
            h1[2] = (_Float16)w0.z; h1[3] = (_Float16)w0.w;
            h1[4] = (_Float16)w1.x; h1[5] = (_Float16)w1.y;
            h1[6] = (_Float16)w1.z; h1[7] = (_Float16)w1.w;
            a0[ko] = h0; a1[ko] = h1;
            ssq0 += u0.x*u0.x + u0.y*u0.y + u0.z*u0.z + u0.w*u0.w
                  + u1.x*u1.x + u1.y*u1.y + u1.z*u1.z + u1.w*u1.w;
            ssq1 += w0.x*w0.x + w0.y*w0.y + w0.z*w0.z + w0.w*w0.w
                  + w1.x*w1.x + w1.y*w1.y + w1.z*w1.z + w1.w*w1.w;
        }
    }
    __syncthreads();   // stage 0 in LDS (barrier drains vmcnt), A ready

    float bv0[4] = {-1e30f, -1e30f, -1e30f, -1e30f};
    float bv1[4] = {-1e30f, -1e30f, -1e30f, -1e30f};
    int bi0[4] = {0, 0, 0, 0};
    int bi1[4] = {0, 0, 0, 0};

    // 16 steps; step s: compute tile (h, s) from buf s&1, prefetch step s+1 into buf (s+1)&1
    #pragma unroll 1
    for (int s = 0; s < 16; ++s) {
        const int cur = s & 1;
        if (s < 15) {
            const int nb = cur ^ 1;
            const _Float16* p0 = bswz + (size_t)(s + 1) * 4096 + t * 8;
            __builtin_amdgcn_global_load_lds((gas_t)(const void*)p0,
                                             (las_t)(void*)(&bb[nb][0][t * 8]), 16, 0, 0);
            const _Float16* p1 = bswz + (size_t)(17 + s) * 4096 + t * 8;
            __builtin_amdgcn_global_load_lds((gas_t)(const void*)p1,
                                             (las_t)(void*)(&bb[nb][1][t * 8]), 16, 0, 0);
        }
        const float bias_nxt = bias[h * 256 + ((s < 15) ? s + 1 : s) * 16 + ln];
        // score = x.e_norm - 0.5*||e_norm||^2 ; one B-frag read feeds both row-sets
        const int c = h * 256 + s * 16 + ln;
        f32x4 acc0 = {-bias_cur, -bias_cur, -bias_cur, -bias_cur};
        f32x4 acc1 = {-bias_cur, -bias_cur, -bias_cur, -bias_cur};
        const half8_t* bp = (const half8_t*)&bb[cur][h][0] + lane;
        #pragma unroll
        for (int ko = 0; ko < 8; ++ko) {
            const half8_t bf = bp[ko * 64];
            acc0 = __builtin_amdgcn_mfma_f32_16x16x32_f16(a0[ko], bf, acc0, 0, 0, 0);
            acc1 = __builtin_amdgcn_mfma_f32_16x16x32_f16(a1[ko], bf, acc1, 0, 0, 0);
        }
        #pragma unroll
        for (int r = 0; r < 4; ++r) {       // D[m][n]: n=ln, m=qd*4+r; ascending c -> strict >
            if (acc0[r] > bv0[r]) { bv0[r] = acc0[r]; bi0[r] = c; }
            if (acc1[r] > bv1[r]) { bv1[r] = acc1[r]; bi1[r] = c; }
        }
        bias_cur = bias_nxt;
        __syncthreads();                    // all reads of cur done; stage s+1 landed
    }

    // per-row argmax across the 16 lanes of each quad
    #pragma unroll
    for (int r = 0; r < 4; ++r) {
        #pragma unroll
        for (int off = 1; off < 16; off <<= 1) {
            const float ov0 = __shfl_xor(bv0[r], off);
            const int   oi0 = __shfl_xor(bi0[r], off);
            if (ov0 > bv0[r] || (ov0 == bv0[r] && oi0 < bi0[r])) { bv0[r] = ov0; bi0[r] = oi0; }
            const float ov1 = __shfl_xor(bv1[r], off);
            const int   oi1 = __shfl_xor(bi1[r], off);
            if (ov1 > bv1[r] || (ov1 == bv1[r] && oi1 < bi1[r])) { bv1[r] = ov1; bi1[r] = oi1; }
        }
    }
    // broadcast row ssq (row m's ssq lives in lanes with ln == m&15)
    float ssA[4], ssB[4];
    #pragma unroll
    for (int r = 0; r < 4; ++r) {
        ssA[r] = __shfl(ssq0, qd * 4 + r);
        ssB[r] = __shfl(ssq1, qd * 4 + r);
    }
    if (ln == 0) {
        #pragma unroll
        for (int r = 0; r < 4; ++r) {
            const int m = rp * 32 + qd * 4 + r;
            lbv[m][h] = bv0[r];      lbi[m][h] = bi0[r];
            lbv[m + 16][h] = bv1[r]; lbi[m + 16][h] = bi1[r];
            if (h == 0) { lssq[m] = ssA[r]; lssq[m + 16] = ssB[r]; }
        }
    }
    __syncthreads();

    // combine halves per row; direct global hist atomic; loss term (no x re-read)
    float term = 0.0f;
    if (t < kBM) {
        const float v0 = lbv[t][0], v1 = lbv[t][1];
        const int i0 = lbi[t][0], i1 = lbi[t][1];
        const bool take1 = (v1 > v0);       // tie -> i0 (always the lower index)
        const int win = take1 ? i1 : i0;
        const float sc = take1 ? v1 : v0;
        lidx[t] = win;
        atomicAdd(&hist[win], 1u);
        const float2 cc = cab[win];
        term = lssq[t] + cc.x + cc.y * sc;
    }
    if (wave < 2) {
        #pragma unroll
        for (int off = 32; off > 0; off >>= 1) term += __shfl_xor(term, off);
        if (lane == 0) lred[wave] = term;
    }
    __syncthreads();
    if (t == 0) atomicAdd(loss_accum, lred[0] + lred[1]);

    // epilogue: write quantized_ = gathered raw codebook rows (128 rows x 1 KB)
    #pragma unroll
    for (int i = 0; i < 4; ++i) {
        const int fi = t + i * 512;         // float4 index within block (2048 total)
        const int r = fi >> 4;
        const int ch = fi & 15;
        const int idx = lidx[r];
        const float4 q = *(const float4*)(emb + (size_t)idx * kD + ch * 4);
        *(float4*)(out + (size_t)(row0 + r) * kD + ch * 4) = q;
    }

    // ---- ticket: last block computes the two scalars (replaces vq_final) ----
    __threadfence();                        // each thread's writes/atomics visible
    __syncthreads();                        // whole block done & fenced
    if (t < 64) {
        unsigned int rank = 0;
        if (t == 0) rank = atomicAdd(cnt, 1u);
        rank = __shfl(rank, 0);
        if (rank == (unsigned int)(gridDim.x - 1)) {   // last block to finish
            __threadfence();
            float sp = 0.0f;
            for (int b = t; b < kM; b += 64) {
                const unsigned int hv = atomicAdd(&hist[b], 0u);   // coherent read
                const float p = (float)hv * (1.0f / 65536.0f);
                sp += p * logf(p + 1e-10f);
            }
            #pragma unroll
            for (int off = 32; off > 0; off >>= 1) sp += __shfl_xor(sp, off);
            if (t == 0) {
                const float lt = atomicAdd(loss_accum, 0.0f);      // coherent read
                out[16777217] = expf(-sp);                          // perplexity
                out[16777216] = lt * (1.0f / 16777216.0f);          // commitment loss
            }
        }
    }
}

extern "C" void kernel_launch(void* const* d_in, const int* in_sizes, int n_in,
                              void* d_out, int out_size, void* d_ws, size_t ws_size,
                              hipStream_t stream) {
    const float* x = (const float*)d_in[0];     // (16,4096,256) fp32
    const float* emb = (const float*)d_in[1];   // (512,256) fp32
    char* ws = (char*)d_ws;
    _Float16* bswz = (_Float16*)ws;                            // 262144 B
    float* bias = (float*)(ws + 262144);                       // 2048 B
    unsigned int* hist = (unsigned int*)(ws + 264192);         // 2048 B
    float* loss = (float*)(ws + 266240);                       // 16 B
    float2* cab = (float2*)(ws + 266256);                      // 4096 B
    unsigned int* cnt = (unsigned int*)(ws + 270352);          // 4 B
    float* out = (float*)d_out;

    vq_prep<<<kM, 64, 0, stream>>>(emb, bswz, bias, cab, hist, loss, cnt);
    vq_main<<<kRows / kBM, 512, 0, stream>>>(x, emb, bswz, bias, cab, hist, loss, cnt, out);
}

// Round 4
// 213.436 us; speedup vs baseline: 1.5249x; 1.5249x over previous
//
#include <hip/hip_runtime.h>

// VQ-VAE quantization forward for MI355X (gfx950).
// outputs (concat in d_out, fp32): quantized_ [16*4096*256], commitment_loss [1], perplexity [1]
//
// v5 = v4 main loop WITHOUT the fused ticket-final (v4's __threadfence-per-block forced
// per-block L2 writeback/invalidate storms -> 4x regression; scalars via separate kernel).
//   - 512 blocks x 512 threads (8 waves). Block owns 128 rows. Wave (rp,h): rows rp*32..+31,
//     code half h (256 codes). A resident in regs; each B-fragment ds_read feeds TWO MFMAs.
//   - B staged via global_load_lds (direct-to-LDS), double-buffered 16-code tiles per half,
//     one barrier per step, shared by all 8 waves: B VMEM = 256 KB/block (vs 2 MB in v3).
//   - Output is exactly the gathered raw codebook row (x + sg(q-x) -> q; (q+q)/2 = q).
//     Loss via ||x||^2 + cA[c] + cB[c]*score, no x re-read.
//   - Histogram: LDS-local + end flush (no global atomic storm, no fences anywhere).
//   - Score path bit-identical to v2/v3 (same fragments, K-order, -bias init, strict-> argmax).

typedef _Float16 half8_t __attribute__((ext_vector_type(8)));
typedef _Float16 half4_t __attribute__((ext_vector_type(4)));
typedef float f32x4 __attribute__((ext_vector_type(4)));

static constexpr int kRows = 65536;   // N*T
static constexpr int kD = 256;
static constexpr int kM = 512;
static constexpr int kBM = 128;       // rows per block

typedef const unsigned int __attribute__((address_space(1)))* gas_t;
typedef unsigned int __attribute__((address_space(3)))* las_t;

// ---------------- prep: normalize codebook -> fp16 in MFMA B-fragment order, bias, cA/cB, zero hist/loss
// swz layout (halves): [group g=c>>4][ko=k>>5][lane = qd*16 + (c&15)][j = k&7], qd=(k>>3)&3.
__global__ void vq_prep(const float* __restrict__ emb, _Float16* __restrict__ swz,
                        float* __restrict__ bias, float2* __restrict__ cab,
                        unsigned int* __restrict__ hist, float* __restrict__ loss) {
    const int j = blockIdx.x;       // code row, 512 blocks
    const int lane = threadIdx.x;   // 64 threads = 1 wave
    float4 v = ((const float4*)(emb + j * kD))[lane];
    float ss = v.x * v.x + v.y * v.y + v.z * v.z + v.w * v.w;
    #pragma unroll
    for (int off = 32; off > 0; off >>= 1) ss += __shfl_xor(ss, off);
    const float s = sqrtf(ss) + 1e-4f;      // ||emb_raw|| + 1e-4
    const float scale = 1.0f / s;
    if (lane == 0) {
        bias[j] = 0.5f * ss * scale * scale;            // 0.5*||e_norm||^2
        cab[j] = make_float2(ss * (1.0f - scale),       // cA = q2*(1-1/s)
                             -2.0f * s);                // cB
    }
    half4_t h;
    h[0] = (_Float16)(v.x * scale);
    h[1] = (_Float16)(v.y * scale);
    h[2] = (_Float16)(v.z * scale);
    h[3] = (_Float16)(v.w * scale);
    const int k0 = lane * 4;
    const int ko = k0 >> 5;
    const int qd = (k0 >> 3) & 3;
    const int jj = k0 & 7;
    const int off_h = (j >> 4) * 4096 + ko * 512 + (qd * 16 + (j & 15)) * 8 + jj;
    *(half4_t*)(swz + off_h) = h;
    if (j == 0) {
        for (int b = lane; b < kM; b += 64) hist[b] = 0u;
        if (lane == 0) loss[0] = 0.0f;
    }
}

// ---------------- main: staged B (1:2 ds_read:MFMA), 32 rows/wave, code-split halves ----------------
__global__ __launch_bounds__(512, 4) void vq_main(
    const float* __restrict__ x, const float* __restrict__ emb,
    const _Float16* __restrict__ bswz, const float* __restrict__ bias,
    const float2* __restrict__ cab, unsigned int* __restrict__ hist,
    float* __restrict__ loss_accum, float* __restrict__ out) {
    __shared__ _Float16 bb[2][2][4096];     // [buf][h][halves] = 32 KB, 16-code tiles
    __shared__ float lbv[kBM][2];           // per-row best score, per code-half
    __shared__ int   lbi[kBM][2];           // per-row best index, per code-half
    __shared__ float lssq[kBM];             // per-row ||x||^2
    __shared__ int   lidx[kBM];             // per-row winner
    __shared__ unsigned int lhist[kM];      // 2048 B
    __shared__ float lred[2];

    const int t = threadIdx.x;              // 0..511, 8 waves
    const int wave = t >> 6;
    const int lane = t & 63;
    const int ln = lane & 15;
    const int qd = lane >> 4;
    const int rp = wave & 3;                // row-pair 0..3
    const int h = wave >> 2;                // code half 0..1
    const int row0 = blockIdx.x * kBM;
    const int r0 = row0 + rp * 32;          // wave's 32 rows

    lhist[t] = 0u;

    // issue stage 0 (tiles g=0 and g=16) into buf 0: 512 thr x 2 x 16 B direct-to-LDS
    {
        const _Float16* s0 = bswz + t * 8;
        __builtin_amdgcn_global_load_lds((gas_t)(const void*)s0,
                                         (las_t)(void*)(&bb[0][0][t * 8]), 16, 0, 0);
        const _Float16* s1 = bswz + 16 * 4096 + t * 8;
        __builtin_amdgcn_global_load_lds((gas_t)(const void*)s1,
                                         (las_t)(void*)(&bb[0][1][t * 8]), 16, 0, 0);
    }
    float bias_cur = bias[h * 256 + ln];

    // A fragments (two 16-row sets), loaded once; ||x||^2 per row in fp32
    half8_t a0[8], a1[8];
    float ssq0 = 0.0f, ssq1 = 0.0f;
    {
        const float* xr0 = x + (size_t)(r0 + ln) * kD + qd * 8;
        const float* xr1 = xr0 + 16 * kD;
        #pragma unroll
        for (int ko = 0; ko < 8; ++ko) {
            const float4 u0 = *(const float4*)(xr0 + ko * 32);
            const float4 u1 = *(const float4*)(xr0 + ko * 32 + 4);
            const float4 w0 = *(const float4*)(xr1 + ko * 32);
            const float4 w1 = *(const float4*)(xr1 + ko * 32 + 4);
            half8_t h0, h1;
            h0[0] = (_Float16)u0.x; h0[1] = (_Float16)u0.y;
            h0[2] = (_Float16)u0.z; h0[3] = (_Float16)u0.w;
            h0[4] = (_Float16)u1.x; h0[5] = (_Float16)u1.y;
            h0[6] = (_Float16)u1.z; h0[7] = (_Float16)u1.w;
            h1[0] = (_Float16)w0.x; h1[1] = (_Float16)w0.y;
            h1[2] = (_Float16)w0.z; h1[3] = (_Float16)w0.w;
            h1[4] = (_Float16)w1.x; h1[5] = (_Float16)w1.y;
            h1[6] = (_Float16)w1.z; h1[7] = (_Float16)w1.w;
            a0[ko] = h0; a1[ko] = h1;
            ssq0 += u0.x*u0.x + u0.y*u0.y + u0.z*u0.z + u0.w*u0.w
                  + u1.x*u1.x + u1.y*u1.y + u1.z*u1.z + u1.w*u1.w;
            ssq1 += w0.x*w0.x + w0.y*w0.y + w0.z*w0.z + w0.w*w0.w
                  + w1.x*w1.x + w1.y*w1.y + w1.z*w1.z + w1.w*w1.w;
        }
    }
    __syncthreads();   // stage 0 in LDS (barrier drains vmcnt), A + lhist init ready

    float bv0[4] = {-1e30f, -1e30f, -1e30f, -1e30f};
    float bv1[4] = {-1e30f, -1e30f, -1e30f, -1e30f};
    int bi0[4] = {0, 0, 0, 0};
    int bi1[4] = {0, 0, 0, 0};

    // 16 steps; step s: compute tile (h, s) from buf s&1, prefetch step s+1 into buf (s+1)&1
    #pragma unroll 1
    for (int s = 0; s < 16; ++s) {
        const int cur = s & 1;
        if (s < 15) {
            const int nb = cur ^ 1;
            const _Float16* p0 = bswz + (size_t)(s + 1) * 4096 + t * 8;
            __builtin_amdgcn_global_load_lds((gas_t)(const void*)p0,
                                             (las_t)(void*)(&bb[nb][0][t * 8]), 16, 0, 0);
            const _Float16* p1 = bswz + (size_t)(17 + s) * 4096 + t * 8;
            __builtin_amdgcn_global_load_lds((gas_t)(const void*)p1,
                                             (las_t)(void*)(&bb[nb][1][t * 8]), 16, 0, 0);
        }
        const float bias_nxt = bias[h * 256 + ((s < 15) ? s + 1 : s) * 16 + ln];
        // score = x.e_norm - 0.5*||e_norm||^2 ; one B-frag read feeds both row-sets
        const int c = h * 256 + s * 16 + ln;
        f32x4 acc0 = {-bias_cur, -bias_cur, -bias_cur, -bias_cur};
        f32x4 acc1 = {-bias_cur, -bias_cur, -bias_cur, -bias_cur};
        const half8_t* bp = (const half8_t*)&bb[cur][h][0] + lane;
        #pragma unroll
        for (int ko = 0; ko < 8; ++ko) {
            const half8_t bf = bp[ko * 64];
            acc0 = __builtin_amdgcn_mfma_f32_16x16x32_f16(a0[ko], bf, acc0, 0, 0, 0);
            acc1 = __builtin_amdgcn_mfma_f32_16x16x32_f16(a1[ko], bf, acc1, 0, 0, 0);
        }
        #pragma unroll
        for (int r = 0; r < 4; ++r) {       // D[m][n]: n=ln, m=qd*4+r; ascending c -> strict >
            if (acc0[r] > bv0[r]) { bv0[r] = acc0[r]; bi0[r] = c; }
            if (acc1[r] > bv1[r]) { bv1[r] = acc1[r]; bi1[r] = c; }
        }
        bias_cur = bias_nxt;
        __syncthreads();                    // all reads of cur done; stage s+1 landed
    }

    // per-row argmax across the 16 lanes of each quad
    #pragma unroll
    for (int r = 0; r < 4; ++r) {
        #pragma unroll
        for (int off = 1; off < 16; off <<= 1) {
            const float ov0 = __shfl_xor(bv0[r], off);
            const int   oi0 = __shfl_xor(bi0[r], off);
            if (ov0 > bv0[r] || (ov0 == bv0[r] && oi0 < bi0[r])) { bv0[r] = ov0; bi0[r] = oi0; }
            const float ov1 = __shfl_xor(bv1[r], off);
            const int   oi1 = __shfl_xor(bi1[r], off);
            if (ov1 > bv1[r] || (ov1 == bv1[r] && oi1 < bi1[r])) { bv1[r] = ov1; bi1[r] = oi1; }
        }
    }
    // broadcast row ssq (row m's ssq lives in lanes with ln == m&15)
    float ssA[4], ssB[4];
    #pragma unroll
    for (int r = 0; r < 4; ++r) {
        ssA[r] = __shfl(ssq0, qd * 4 + r);
        ssB[r] = __shfl(ssq1, qd * 4 + r);
    }
    if (ln == 0) {
        #pragma unroll
        for (int r = 0; r < 4; ++r) {
            const int m = rp * 32 + qd * 4 + r;
            lbv[m][h] = bv0[r];      lbi[m][h] = bi0[r];
            lbv[m + 16][h] = bv1[r]; lbi[m + 16][h] = bi1[r];
            if (h == 0) { lssq[m] = ssA[r]; lssq[m + 16] = ssB[r]; }
        }
    }
    __syncthreads();

    // combine halves per row; LDS hist; loss term (no x re-read)
    float term = 0.0f;
    if (t < kBM) {
        const float v0 = lbv[t][0], v1 = lbv[t][1];
        const int i0 = lbi[t][0], i1 = lbi[t][1];
        const bool take1 = (v1 > v0);       // tie -> i0 (always the lower index)
        const int win = take1 ? i1 : i0;
        const float sc = take1 ? v1 : v0;
        lidx[t] = win;
        atomicAdd(&lhist[win], 1u);
        const float2 cc = cab[win];
        term = lssq[t] + cc.x + cc.y * sc;
    }
    if (wave < 2) {
        #pragma unroll
        for (int off = 32; off > 0; off >>= 1) term += __shfl_xor(term, off);
        if (lane == 0) lred[wave] = term;
    }
    __syncthreads();
    if (t == 0) atomicAdd(loss_accum, lred[0] + lred[1]);

    // epilogue: write quantized_ = gathered raw codebook rows (128 rows x 1 KB)
    #pragma unroll
    for (int i = 0; i < 4; ++i) {
        const int fi = t + i * 512;         // float4 index within block (2048 total)
        const int r = fi >> 4;
        const int ch = fi & 15;
        const int idx = lidx[r];
        const float4 q = *(const float4*)(emb + (size_t)idx * kD + ch * 4);
        *(float4*)(out + (size_t)(row0 + r) * kD + ch * 4) = q;
    }

    // flush histogram (skip zero bins); lhist final since the barrier above
    const unsigned int h0 = lhist[t];
    if (h0) atomicAdd(&hist[t], h0);
}

// ---------------- final: scalars ----------------
__global__ void vq_final(const unsigned int* __restrict__ hist,
                         const float* __restrict__ loss_accum,
                         float* __restrict__ out) {
    const int t = threadIdx.x;  // 256 threads
    __shared__ float sr[4];
    float s = 0.0f;
    for (int b = t; b < kM; b += 256) {
        const float p = (float)hist[b] * (1.0f / 65536.0f);
        s += p * logf(p + 1e-10f);
    }
    #pragma unroll
    for (int off = 32; off > 0; off >>= 1) s += __shfl_xor(s, off);
    if ((t & 63) == 0) sr[t >> 6] = s;
    __syncthreads();
    if (t == 0) {
        const float tot = sr[0] + sr[1] + sr[2] + sr[3];
        out[16777217] = expf(-tot);                           // perplexity
        out[16777216] = loss_accum[0] * (1.0f / 16777216.0f); // commitment loss
    }
}

extern "C" void kernel_launch(void* const* d_in, const int* in_sizes, int n_in,
                              void* d_out, int out_size, void* d_ws, size_t ws_size,
                              hipStream_t stream) {
    const float* x = (const float*)d_in[0];     // (16,4096,256) fp32
    const float* emb = (const float*)d_in[1];   // (512,256) fp32
    char* ws = (char*)d_ws;
    _Float16* bswz = (_Float16*)ws;                            // 262144 B
    float* bias = (float*)(ws + 262144);                       // 2048 B
    unsigned int* hist = (unsigned int*)(ws + 264192);         // 2048 B
    float* loss = (float*)(ws + 266240);                       // 16 B
    float2* cab = (float2*)(ws + 266256);                      // 4096 B
    float* out = (float*)d_out;

    vq_prep<<<kM, 64, 0, stream>>>(emb, bswz, bias, cab, hist, loss);
    vq_main<<<kRows / kBM, 512, 0, stream>>>(x, emb, bswz, bias, cab, hist, loss, out);
    vq_final<<<1, 256, 0, stream>>>(hist, loss, out);
}